// Round 1
// baseline (148.621 us; speedup 1.0000x reference)
//
#include <hip/hip_runtime.h>
#include <math.h>

// Problem constants (from setup_inputs): src (N,C,D,H,W) = (2,1,160,192,160) fp32
#define N_ 2
#define C_ 1
#define D_ 160
#define H_ 192
#define W_ 160
#define DHW_ (D_*H_*W_)          // 4,915,200
#define TOTAL_ (N_*DHW_)         // 9,830,400
#define BLOCKS_PER_N_ (DHW_/256) // 19,200 (divides exactly)

__device__ __forceinline__ void matmul3(const float A[3][3], const float B[3][3], float C[3][3]) {
    #pragma unroll
    for (int i = 0; i < 3; ++i)
        #pragma unroll
        for (int j = 0; j < 3; ++j)
            C[i][j] = A[i][0]*B[0][j] + A[i][1]*B[1][j] + A[i][2]*B[2][j];
}

// Builds mat (N,3,4), replicating the torch/jax column-stacking exactly.
// Writes it into the tail of d_out (the tuple's 2nd output); the sample
// kernel re-reads it from there (same stream => ordered).
__global__ void build_mat_kernel(const float* __restrict__ affine,
                                 const float* __restrict__ scale,
                                 const float* __restrict__ translate,
                                 const float* __restrict__ shear,
                                 float* __restrict__ mat_out) {
    int n = threadIdx.x;
    if (n >= N_) return;
    float tx = affine[n*3+0], ty = affine[n*3+1], tz = affine[n*3+2];
    float sx = scale[n*3+0],  sy = scale[n*3+1],  sz = scale[n*3+2];
    float t_xy = tanf(shear[n*6+0]), t_xz = tanf(shear[n*6+1]);
    float t_yx = tanf(shear[n*6+2]), t_yz = tanf(shear[n*6+3]);
    float t_zx = tanf(shear[n*6+4]), t_zy = tanf(shear[n*6+5]);
    float cx = cosf(tx), sxv = sinf(tx);
    float cy = cosf(ty), syv = sinf(ty);
    float cz = cosf(tz), szv = sinf(tz);
    // mat3(c0,c1,c2) stacks args as COLUMNS; expressed here row-major:
    float RX[3][3] = {{1,0,0},{0,cx,sxv},{0,-sxv,cx}};
    float RY[3][3] = {{cy,0,-syv},{0,1,0},{syv,0,cy}};
    float RZ[3][3] = {{cz,szv,0},{-szv,cz,0},{0,0,1}};
    float SC[3][3] = {{sx,0,0},{0,sy,0},{0,0,sz}};
    float SH[3][3] = {{1,t_yx,t_zx},{t_xy,1,t_zy},{t_xz,t_yz,1}};
    float M1[3][3], M2[3][3], M3[3][3], M4[3][3];
    matmul3(RY, RX, M1);   // rot_y @ rot_x
    matmul3(RZ, M1, M2);   // rot_z @ ...
    matmul3(SC, M2, M3);   // scale @ ...
    matmul3(SH, M3, M4);   // shear @ ...
    #pragma unroll
    for (int i = 0; i < 3; ++i) {
        #pragma unroll
        for (int j = 0; j < 3; ++j)
            mat_out[n*12 + i*4 + j] = M4[i][j];
        mat_out[n*12 + i*4 + 3] = translate[n*3 + i];
    }
}

__global__ __launch_bounds__(256)
void affine_sample_kernel(const float* __restrict__ src,
                          const float* __restrict__ mat,   // tail of d_out
                          float* __restrict__ out) {
    // n is wave-uniform (derived from blockIdx only) -> mat loads scalarize/cache.
    int n     = blockIdx.x / BLOCKS_PER_N_;
    int local = (blockIdx.x % BLOCKS_PER_N_) * 256 + threadIdx.x;  // < DHW_

    int w = local % W_;
    int t = local / W_;
    int h = t % H_;
    int d = t / H_;

    const float* m = mat + n * 12;

    // align_corners=True linspace coords
    float x = -1.0f + w * (2.0f / (W_ - 1));
    float y = -1.0f + h * (2.0f / (H_ - 1));
    float z = -1.0f + d * (2.0f / (D_ - 1));

    float gx = m[0]*x + m[1]*y + m[2]*z  + m[3];
    float gy = m[4]*x + m[5]*y + m[6]*z  + m[7];
    float gz = m[8]*x + m[9]*y + m[10]*z + m[11];

    float ix = (gx + 1.0f) * 0.5f * (W_ - 1);
    float iy = (gy + 1.0f) * 0.5f * (H_ - 1);
    float iz = (gz + 1.0f) * 0.5f * (D_ - 1);

    float fx = floorf(ix), fy = floorf(iy), fz = floorf(iz);
    float wx = ix - fx, wy = iy - fy, wz = iz - fz;
    int x0 = (int)fx, y0 = (int)fy, z0 = (int)fz;

    const float* s = src + n * DHW_;
    float acc = 0.0f;
    #pragma unroll
    for (int dz = 0; dz < 2; ++dz) {
        int  zi  = z0 + dz;
        bool vz  = (zi >= 0) & (zi < D_);
        int  zc  = min(max(zi, 0), D_ - 1);
        float wzz = dz ? wz : 1.0f - wz;
        #pragma unroll
        for (int dy = 0; dy < 2; ++dy) {
            int  yi  = y0 + dy;
            bool vzy = vz & (yi >= 0) & (yi < H_);
            int  yc  = min(max(yi, 0), H_ - 1);
            float wzy = wzz * (dy ? wy : 1.0f - wy);
            int rowoff = (zc * H_ + yc) * W_;
            #pragma unroll
            for (int dx = 0; dx < 2; ++dx) {
                int  xi = x0 + dx;
                bool v  = vzy & (xi >= 0) & (xi < W_);
                int  xc = min(max(xi, 0), W_ - 1);
                float ww = wzy * (dx ? wx : 1.0f - wx);
                float val = v ? s[rowoff + xc] : 0.0f;   // clamped addr is always in-bounds
                acc += ww * val;
            }
        }
    }
    out[n * DHW_ + local] = acc;
}

extern "C" void kernel_launch(void* const* d_in, const int* in_sizes, int n_in,
                              void* d_out, int out_size, void* d_ws, size_t ws_size,
                              hipStream_t stream) {
    const float* src       = (const float*)d_in[0];
    const float* affine    = (const float*)d_in[1];
    const float* scale     = (const float*)d_in[2];
    const float* translate = (const float*)d_in[3];
    const float* shear     = (const float*)d_in[4];

    float* out     = (float*)d_out;
    float* mat_out = out + TOTAL_;   // tuple output #2: (N,3,4) flat

    build_mat_kernel<<<1, 64, 0, stream>>>(affine, scale, translate, shear, mat_out);
    affine_sample_kernel<<<N_ * BLOCKS_PER_N_, 256, 0, stream>>>(src, mat_out, out);
}

// Round 2
// 147.601 us; speedup vs baseline: 1.0069x; 1.0069x over previous
//
#include <hip/hip_runtime.h>
#include <math.h>

// Problem constants (from setup_inputs): src (N,C,D,H,W) = (2,1,160,192,160) fp32
#define N_ 2
#define C_ 1
#define D_ 160
#define H_ 192
#define W_ 160
#define HW_ (H_*W_)              // 30,720
#define DHW_ (D_*H_*W_)          // 4,915,200
#define TOTAL_ (N_*DHW_)         // 9,830,400
#define BLOCKS_PER_N_ (DHW_/256) // 19,200
#define NWG_ (TOTAL_/256)        // 38,400 (divisible by 8)
#define NXCD_ 8

__device__ __forceinline__ void matmul3(const float A[3][3], const float B[3][3], float C[3][3]) {
    #pragma unroll
    for (int i = 0; i < 3; ++i)
        #pragma unroll
        for (int j = 0; j < 3; ++j)
            C[i][j] = A[i][0]*B[0][j] + A[i][1]*B[1][j] + A[i][2]*B[2][j];
}

// Builds mat (N,3,4) into the tail of d_out (tuple output #2).
__global__ void build_mat_kernel(const float* __restrict__ affine,
                                 const float* __restrict__ scale,
                                 const float* __restrict__ translate,
                                 const float* __restrict__ shear,
                                 float* __restrict__ mat_out) {
    int n = threadIdx.x;
    if (n >= N_) return;
    float tx = affine[n*3+0], ty = affine[n*3+1], tz = affine[n*3+2];
    float sx = scale[n*3+0],  sy = scale[n*3+1],  sz = scale[n*3+2];
    float t_xy = tanf(shear[n*6+0]), t_xz = tanf(shear[n*6+1]);
    float t_yx = tanf(shear[n*6+2]), t_yz = tanf(shear[n*6+3]);
    float t_zx = tanf(shear[n*6+4]), t_zy = tanf(shear[n*6+5]);
    float cx = cosf(tx), sxv = sinf(tx);
    float cy = cosf(ty), syv = sinf(ty);
    float cz = cosf(tz), szv = sinf(tz);
    float RX[3][3] = {{1,0,0},{0,cx,sxv},{0,-sxv,cx}};
    float RY[3][3] = {{cy,0,-syv},{0,1,0},{syv,0,cy}};
    float RZ[3][3] = {{cz,szv,0},{-szv,cz,0},{0,0,1}};
    float SC[3][3] = {{sx,0,0},{0,sy,0},{0,0,sz}};
    float SH[3][3] = {{1,t_yx,t_zx},{t_xy,1,t_zy},{t_xz,t_yz,1}};
    float M1[3][3], M2[3][3], M3[3][3], M4[3][3];
    matmul3(RY, RX, M1);
    matmul3(RZ, M1, M2);
    matmul3(SC, M2, M3);
    matmul3(SH, M3, M4);
    #pragma unroll
    for (int i = 0; i < 3; ++i) {
        #pragma unroll
        for (int j = 0; j < 3; ++j)
            mat_out[n*12 + i*4 + j] = M4[i][j];
        mat_out[n*12 + i*4 + 3] = translate[n*3 + i];
    }
}

__global__ __launch_bounds__(256)
void affine_sample_kernel(const float* __restrict__ src,
                          const float* __restrict__ mat,   // tail of d_out
                          float* __restrict__ out) {
    // XCD-chunked swizzle: HW assigns blockIdx round-robin to the 8 XCDs;
    // remap so each XCD owns a CONTIGUOUS 4800-block slab (a 40-d-slice slab)
    // -> the two z-slices each block gathers stay hot in that XCD's private L2.
    int bid = blockIdx.x;
    int swz = (bid & (NXCD_-1)) * (NWG_/NXCD_) + (bid >> 3);

    int n     = swz / BLOCKS_PER_N_;            // wave-uniform
    int local = (swz % BLOCKS_PER_N_) * 256 + threadIdx.x;

    int w = local % W_;
    int t = local / W_;
    int h = t % H_;
    int d = t / H_;

    const float* m = mat + n * 12;

    float x = -1.0f + w * (2.0f / (W_ - 1));
    float y = -1.0f + h * (2.0f / (H_ - 1));
    float z = -1.0f + d * (2.0f / (D_ - 1));

    float gx = m[0]*x + m[1]*y + m[2]*z  + m[3];
    float gy = m[4]*x + m[5]*y + m[6]*z  + m[7];
    float gz = m[8]*x + m[9]*y + m[10]*z + m[11];

    float ix = (gx + 1.0f) * 0.5f * (W_ - 1);
    float iy = (gy + 1.0f) * 0.5f * (H_ - 1);
    float iz = (gz + 1.0f) * 0.5f * (D_ - 1);

    float fx = floorf(ix), fy = floorf(iy), fz = floorf(iz);
    float wx = ix - fx, wy = iy - fy, wz = iz - fz;
    int x0 = (int)fx, y0 = (int)fy, z0 = (int)fz;

    const float* s = src + n * DHW_;
    float acc;

    // Interior iff all 8 corners in-bounds: 0 <= c0 && c0+1 <= dim-1.
    bool interior = ((unsigned)x0 < (unsigned)(W_-1)) &
                    ((unsigned)y0 < (unsigned)(H_-1)) &
                    ((unsigned)z0 < (unsigned)(D_-1));

    if (__all(interior)) {
        // Fast path: one base pointer, constant offsets, lerp factorization.
        const float* p = s + (z0 * H_ + y0) * W_ + x0;
        float v000 = p[0],        v001 = p[1];
        float v010 = p[W_],       v011 = p[W_ + 1];
        float v100 = p[HW_],      v101 = p[HW_ + 1];
        float v110 = p[HW_ + W_], v111 = p[HW_ + W_ + 1];
        float c00 = v000 + wx * (v001 - v000);
        float c01 = v010 + wx * (v011 - v010);
        float c10 = v100 + wx * (v101 - v100);
        float c11 = v110 + wx * (v111 - v110);
        float c0  = c00 + wy * (c01 - c00);
        float c1  = c10 + wy * (c11 - c10);
        acc = c0 + wz * (c1 - c0);
    } else {
        // Boundary path: clamp + zero-pad, exactly like the reference.
        acc = 0.0f;
        #pragma unroll
        for (int dz = 0; dz < 2; ++dz) {
            int  zi  = z0 + dz;
            bool vz  = (zi >= 0) & (zi < D_);
            int  zc  = min(max(zi, 0), D_ - 1);
            float wzz = dz ? wz : 1.0f - wz;
            #pragma unroll
            for (int dy = 0; dy < 2; ++dy) {
                int  yi  = y0 + dy;
                bool vzy = vz & (yi >= 0) & (yi < H_);
                int  yc  = min(max(yi, 0), H_ - 1);
                float wzy = wzz * (dy ? wy : 1.0f - wy);
                int rowoff = (zc * H_ + yc) * W_;
                #pragma unroll
                for (int dx = 0; dx < 2; ++dx) {
                    int  xi = x0 + dx;
                    bool v  = vzy & (xi >= 0) & (xi < W_);
                    int  xc = min(max(xi, 0), W_ - 1);
                    float ww = wzy * (dx ? wx : 1.0f - wx);
                    float val = v ? s[rowoff + xc] : 0.0f;
                    acc += ww * val;
                }
            }
        }
    }
    out[n * DHW_ + local] = acc;
}

extern "C" void kernel_launch(void* const* d_in, const int* in_sizes, int n_in,
                              void* d_out, int out_size, void* d_ws, size_t ws_size,
                              hipStream_t stream) {
    const float* src       = (const float*)d_in[0];
    const float* affine    = (const float*)d_in[1];
    const float* scale     = (const float*)d_in[2];
    const float* translate = (const float*)d_in[3];
    const float* shear     = (const float*)d_in[4];

    float* out     = (float*)d_out;
    float* mat_out = out + TOTAL_;   // tuple output #2: (N,3,4) flat

    build_mat_kernel<<<1, 64, 0, stream>>>(affine, scale, translate, shear, mat_out);
    affine_sample_kernel<<<NWG_, 256, 0, stream>>>(src, mat_out, out);
}